// Round 8
// baseline (184.030 us; speedup 1.0000x reference)
//
#include <hip/hip_runtime.h>

#define B_ 2
#define S_ 2048
#define D_ 1024
#define H_ 16
#define DK_ 64
#define M_ (B_ * S_)   // 4096
#define N_ (3 * D_)    // 3072

typedef __bf16 bf16x8 __attribute__((ext_vector_type(8)));
typedef short s8vec __attribute__((ext_vector_type(8)));
typedef float f4vec __attribute__((ext_vector_type(4)));

static __device__ __forceinline__ ushort f2b(float f) {
  union { float f; unsigned u; } v; v.f = f;
  unsigned u = v.u;
  u += 0x7FFFu + ((u >> 16) & 1u);   // RNE to bf16
  return (ushort)(u >> 16);
}

static __device__ __forceinline__ unsigned pk2(float a, float b) {
#if __has_builtin(__builtin_amdgcn_cvt_pk_bf16_f32)
  typedef __bf16 b2 __attribute__((ext_vector_type(2)));
  b2 r = __builtin_amdgcn_cvt_pk_bf16_f32(a, b);
  return __builtin_bit_cast(unsigned, r);
#else
  return (unsigned)f2b(a) | ((unsigned)f2b(b) << 16);
#endif
}

static __device__ __forceinline__ float fexp2(float x) {
#if __has_builtin(__builtin_amdgcn_exp2f)
  return __builtin_amdgcn_exp2f(x);
#else
  return exp2f(x);
#endif
}

static __device__ __forceinline__ f4vec mfma16(s8vec a, s8vec b, f4vec c) {
  return __builtin_amdgcn_mfma_f32_16x16x32_bf16(
      __builtin_bit_cast(bf16x8, a), __builtin_bit_cast(bf16x8, b), c, 0, 0, 0);
}

static __device__ __forceinline__ void gl_lds16(const ushort* g, ushort* l) {
  __builtin_amdgcn_global_load_lds(
      (const __attribute__((address_space(1))) unsigned*)g,
      (__attribute__((address_space(3))) unsigned*)l, 16, 0, 0);
}

// raw workgroup barrier draining LDS only; in-flight global->VGPR loads cross it
static __device__ __forceinline__ void wg_barrier_lds() {
  asm volatile("" ::: "memory");
  __builtin_amdgcn_s_waitcnt(0xC07F);   // vmcnt(63) expcnt(7) lgkmcnt(0)
  __builtin_amdgcn_s_barrier();
  asm volatile("" ::: "memory");
}

// ---- merged conversion kernel: blocks [0,4096) do x, [4096,4864) do W ----
__global__ __launch_bounds__(256) void cvt_all(const float* __restrict__ x,
                                               const float* __restrict__ Wq,
                                               const float* __restrict__ Wk,
                                               const float* __restrict__ Wv,
                                               ushort* __restrict__ xb,
                                               ushort* __restrict__ wbt) {
  const int t = threadIdx.x;
  if (blockIdx.x < 4096) {
    int i = blockIdx.x * 256 + t;
    float4 v = ((const float4*)x)[i];
    ushort4 o;
    o.x = f2b(v.x); o.y = f2b(v.y); o.z = f2b(v.z); o.w = f2b(v.w);
    ((ushort4*)xb)[i] = o;
  } else {
    __shared__ ushort T[64 * 72];
    int bid = blockIdx.x - 4096;            // 0..767: (w, h, d-tile)
    int w = bid >> 8, rem = bid & 255;
    int h = rem >> 4, d0 = (rem & 15) * 64;
    const float* W = (w == 0) ? Wq : (w == 1) ? Wk : Wv;
    const float* src = W + (size_t)h * 65536 + (size_t)d0 * 64;   // [64 d][64 k]
#pragma unroll
    for (int j = 0; j < 4; ++j) {
      int idx = j * 256 + t;
      int dr = idx >> 4, kc = (idx & 15) * 4;
      float4 v = *(const float4*)(src + dr * 64 + kc);
      T[(kc + 0) * 72 + dr] = f2b(v.x);
      T[(kc + 1) * 72 + dr] = f2b(v.y);
      T[(kc + 2) * 72 + dr] = f2b(v.z);
      T[(kc + 3) * 72 + dr] = f2b(v.w);
    }
    __syncthreads();
    const int kk = t >> 2, dcg = (t & 3) * 16;
    ushort* dst = wbt + ((size_t)w * 1024 + h * 64 + kk) * 1024 + d0 + dcg;
    *(s8vec*)dst       = *(const s8vec*)&T[kk * 72 + dcg];
    *(s8vec*)(dst + 8) = *(const s8vec*)&T[kk * 72 + dcg + 8];
  }
}

// ---- fused QKV projection: C[4096][3072] = X[4096][1024] @ Wbt^T (m97 structure) ----
// Q output pre-scaled by log2(e) so attn uses raw exp2.  (unchanged control)
__global__ __launch_bounds__(256) void proj_gemm(const ushort* __restrict__ xb,
                                                 const ushort* __restrict__ wbt,
                                                 ushort* __restrict__ qkv) {
  __shared__ __attribute__((aligned(16))) ushort As[128 * 64];
  __shared__ __attribute__((aligned(16))) ushort Bs[128 * 64];
  const int tid = threadIdx.x, wid = tid >> 6, lane = tid & 63;
  const int quad = lane >> 4, l15 = lane & 15;
  const int wm = wid & 1, wn = wid >> 1;
  const int m0 = blockIdx.x * 128, n0 = blockIdx.y * 128;

  f4vec acc[4][4];
#pragma unroll
  for (int mb = 0; mb < 4; mb++)
#pragma unroll
    for (int nb = 0; nb < 4; nb++)
#pragma unroll
      for (int i = 0; i < 4; i++) acc[mb][nb][i] = 0.f;

  const int sr = tid >> 3, sg = tid & 7;
  const int lg = sg ^ (sr & 7);
  const ushort* Ab = xb + (size_t)m0 * D_;
  const ushort* Bb = wbt + (size_t)n0 * D_;

  for (int k0 = 0; k0 < D_; k0 += 64) {
    __syncthreads();
#pragma unroll
    for (int j = 0; j < 4; ++j) {
      int r = j * 32 + sr;
      gl_lds16(Ab + (size_t)r * D_ + k0 + lg * 8, &As[j * 2048 + wid * 512]);
      gl_lds16(Bb + (size_t)r * D_ + k0 + lg * 8, &Bs[j * 2048 + wid * 512]);
    }
    __syncthreads();

#pragma unroll
    for (int kb = 0; kb < 2; ++kb) {
      s8vec af[4], bf[4];
#pragma unroll
      for (int mb = 0; mb < 4; ++mb) {
        int m = wm * 64 + mb * 16 + l15;
        int gpos = (kb * 4 + quad) ^ (m & 7);
        af[mb] = *(const s8vec*)&As[m * 64 + gpos * 8];
      }
#pragma unroll
      for (int nb = 0; nb < 4; ++nb) {
        int n = wn * 64 + nb * 16 + l15;
        int gpos = (kb * 4 + quad) ^ (n & 7);
        bf[nb] = *(const s8vec*)&Bs[n * 64 + gpos * 8];
      }
#pragma unroll
      for (int mb = 0; mb < 4; ++mb)
#pragma unroll
        for (int nb = 0; nb < 4; ++nb)
          acc[mb][nb] = mfma16(af[mb], bf[nb], acc[mb][nb]);
    }
  }

  const size_t per = (size_t)B_ * H_ * S_ * DK_;
  const int w = n0 >> 10;
  if (w == 2) {
    ushort* vt = qkv + 2 * per;
#pragma unroll
    for (int mb = 0; mb < 4; ++mb)
#pragma unroll
      for (int nb = 0; nb < 4; ++nb)
#pragma unroll
        for (int i = 0; i < 4; ++i) {
          int m = m0 + wm * 64 + mb * 16 + quad * 4 + i;
          int b = m >> 11, s = m & 2047;
          int n1 = (n0 & 1023) + wn * 64 + nb * 16 + l15;
          vt[((size_t)b * 1024 + n1) * S_ + s] = f2b(acc[mb][nb][i]);
        }
  } else {
    const float qs = (w == 0) ? 1.44269504f : 1.0f;   // log2(e) pre-scale
#pragma unroll
    for (int mb = 0; mb < 4; ++mb)
#pragma unroll
      for (int nb = 0; nb < 4; ++nb)
#pragma unroll
        for (int i = 0; i < 4; ++i) {
          int m = m0 + wm * 64 + mb * 16 + quad * 4 + i;
          int b = m >> 11, s = m & 2047;
          int n1 = (n0 & 1023) + wn * 64 + nb * 16 + l15;
          qkv[(size_t)w * per + (((size_t)b * H_ + (n1 >> 6)) * S_ + s) * 64 + (n1 & 63)] =
              f2b(acc[mb][nb][i] * qs);
        }
  }
}

// ---- flash attention v6: K-split 2 (additive partials, no-max softmax).
// grid (16, 32, 2) = 1024 blocks -> 4 blocks/CU, 16 waves/CU.
// 4 waves x 32 Q-rows, K-tile 64, S^T layout; lsum via MFMA ones-row in V^T
// (16 extra A-rows of 1.0 -> 5th O-block holds sum(P) per q, no VALU adds).
__global__ __launch_bounds__(256) void attn(const ushort* __restrict__ qg,
                                            const ushort* __restrict__ kg,
                                            const ushort* __restrict__ vtg,
                                            float* __restrict__ opart,
                                            float* __restrict__ lpart) {
  __shared__ __attribute__((aligned(16))) ushort Ks[64 * 64];      // [key][d], chunk-XOR
  __shared__ __attribute__((aligned(16))) ushort Vt[80 * 64];      // [dv(+ones)][key]
  __shared__ __attribute__((aligned(16))) ushort Ps[4][32 * 64];   // [q][key], chunk-XOR
  const int qt = blockIdx.x, bh = blockIdx.y, ks = blockIdx.z;
  const int b = bh >> 4, h = bh & 15;
  const int tid = threadIdx.x, wid = tid >> 6, lane = tid & 63;
  const int quad = lane >> 4, l15 = lane & 15, l7 = l15 & 7;
  const int kt0 = ks * (S_ / 128);          // 16 tiles of 64 keys per split

  // ones rows 64..79 of Vt (bf16 1.0 = 0x3F80), written once
  if (tid < 128) {
    ushort* p = &Vt[(64 + (tid >> 3)) * 64 + (tid & 7) * 8];
#pragma unroll
    for (int j = 0; j < 8; ++j) p[j] = 0x3F80;
  }

  // Q fragments (B-operand: n=q=l15+16mb, k=d)
  const ushort* qbase = qg + ((size_t)bh * S_ + qt * 128 + wid * 32) * DK_;
  s8vec aq[2][2];
#pragma unroll
  for (int mb = 0; mb < 2; mb++) {
    aq[mb][0] = *(const s8vec*)(qbase + (size_t)(mb * 16 + l15) * DK_ + quad * 8);
    aq[mb][1] = *(const s8vec*)(qbase + (size_t)(mb * 16 + l15) * DK_ + 32 + quad * 8);
  }

  f4vec o[2][5];          // O^T[dv-block nb][q]; nb=4 is the ones-row (lsum)
#pragma unroll
  for (int mb = 0; mb < 2; mb++)
#pragma unroll
    for (int nb = 0; nb < 5; nb++)
#pragma unroll
      for (int i = 0; i < 4; i++) o[mb][nb][i] = 0.f;

  // staging: thread t -> rows {r, r+32} of K and V^T; chunk slot gs
  const int r = tid >> 3, gs = tid & 7;
  const int gk = gs ^ (r & 7);
  const ushort* kb_ = kg + (size_t)bh * S_ * DK_;
  const ushort* vb_ = vtg + (size_t)bh * 64 * S_;

  s8vec kpre[2], vpre[2];
  kpre[0] = *(const s8vec*)(kb_ + (size_t)(kt0 * 64 + r) * DK_ + gk * 8);
  kpre[1] = *(const s8vec*)(kb_ + (size_t)(kt0 * 64 + r + 32) * DK_ + gk * 8);
  vpre[0] = *(const s8vec*)(vb_ + (size_t)r * S_ + kt0 * 64 + gk * 8);
  vpre[1] = *(const s8vec*)(vb_ + (size_t)(r + 32) * S_ + kt0 * 64 + gk * 8);

  for (int kt = kt0; kt < kt0 + S_ / 128; ++kt) {
    wg_barrier_lds();                      // readers of previous tile done
    *(s8vec*)&Ks[r * 64 + gs * 8]        = kpre[0];   // vmcnt auto-waits
    *(s8vec*)&Ks[(r + 32) * 64 + gs * 8] = kpre[1];
    *(s8vec*)&Vt[r * 64 + gs * 8]        = vpre[0];
    *(s8vec*)&Vt[(r + 32) * 64 + gs * 8] = vpre[1];
    if (kt + 1 < kt0 + S_ / 128) {        // prefetch next tile; stays in flight
      const ushort* kn = kb_ + (size_t)((kt + 1) * 64 + r) * DK_ + gk * 8;
      kpre[0] = *(const s8vec*)(kn);
      kpre[1] = *(const s8vec*)(kn + (size_t)32 * DK_);
      const ushort* vn = vb_ + (size_t)r * S_ + (kt + 1) * 64 + gk * 8;
      vpre[0] = *(const s8vec*)(vn);
      vpre[1] = *(const s8vec*)(vn + (size_t)32 * S_);
    }
    wg_barrier_lds();                      // staging writes visible

    // S^T = K Q^T : A-frag = Ks rows (m=key), B = Q regs (n=q)
    f4vec sct[2][4];
#pragma unroll
    for (int nb = 0; nb < 4; nb++) {
      const int row = nb * 16 + l15;
      s8vec ak0 = *(const s8vec*)&Ks[row * 64 + ((0 + quad) ^ l7) * 8];
      s8vec ak1 = *(const s8vec*)&Ks[row * 64 + ((4 + quad) ^ l7) * 8];
#pragma unroll
      for (int mb = 0; mb < 2; mb++) {
        f4vec z;
#pragma unroll
        for (int i = 0; i < 4; i++) z[i] = 0.f;
        z = mfma16(ak0, aq[mb][0], z);
        sct[mb][nb] = mfma16(ak1, aq[mb][1], z);
      }
    }

    // softmax: exp2 (Q pre-scaled), pack 4 consecutive keys -> one b64 LDS write
#pragma unroll
    for (int mb = 0; mb < 2; mb++) {
      const int q = mb * 16 + l15;
#pragma unroll
      for (int nb = 0; nb < 4; nb++) {
        f4vec p;
#pragma unroll
        for (int i = 0; i < 4; i++) p[i] = fexp2(sct[mb][nb][i]);
        unsigned p01 = pk2(p[0], p[1]);
        unsigned p23 = pk2(p[2], p[3]);
        const int c = (nb * 2 + (quad >> 1)) ^ l7;
        *(uint2*)&Ps[wid][q * 64 + c * 8 + (quad & 1) * 4] = make_uint2(p01, p23);
      }
    }
    // no barrier: Ps[wid] per-wave

    // O^T += V^T P^T : A = Vt rows (m=dv, nb=4 -> ones/lsum), B = Ps rows (n=q)
#pragma unroll
    for (int kc = 0; kc < 2; kc++) {
      s8vec ap[2];
#pragma unroll
      for (int mb = 0; mb < 2; mb++)
        ap[mb] = *(const s8vec*)&Ps[wid][(mb * 16 + l15) * 64 + ((kc * 4 + quad) ^ l7) * 8];
#pragma unroll
      for (int nb = 0; nb < 5; nb++) {
        s8vec av = *(const s8vec*)&Vt[(nb * 16 + l15) * 64 + ((kc * 4 + quad) ^ l7) * 8];
        o[0][nb] = mfma16(av, ap[0], o[0][nb]);
        o[1][nb] = mfma16(av, ap[1], o[1][nb]);
      }
    }
  }

  // epilogue: raw partial O^T -> opart[ks][b][s][h*64+dv] fp32 (no normalize);
  // lsum (= o[mb][4][*], identical across quads/i) -> lpart[ks][bh*2048+s]
  float* ob = opart + (size_t)ks * (M_ * (size_t)D_);
#pragma unroll
  for (int mb = 0; mb < 2; mb++) {
    const int s = qt * 128 + wid * 32 + mb * 16 + l15;
    float* orow = ob + ((size_t)b * S_ + s) * D_ + h * DK_;
#pragma unroll
    for (int nb = 0; nb < 4; nb++) {
      float4 v;
      v.x = o[mb][nb][0]; v.y = o[mb][nb][1];
      v.z = o[mb][nb][2]; v.w = o[mb][nb][3];
      *(float4*)(orow + nb * 16 + quad * 4) = v;
    }
    if (quad == 0)
      lpart[(size_t)ks * 65536 + (size_t)bh * S_ + s] = o[mb][4][0];
  }
}

// ---- combine the two K-split partials: out = (O0+O1) / (l0+l1) ----
__global__ __launch_bounds__(256) void attn_reduce(const float* __restrict__ opart,
                                                   const float* __restrict__ lpart,
                                                   float* __restrict__ out) {
  const int i = blockIdx.x * 256 + threadIdx.x;       // float4 index, 1M total
  const float4 a = ((const float4*)opart)[i];
  const float4 c = ((const float4*)(opart + (size_t)M_ * D_))[i];
  const int e = i * 4;
  const int row = e >> 10;                 // b*2048 + s
  const int d = e & 1023;
  const int idx = ((row >> 11) * 16 + (d >> 6)) * S_ + (row & 2047);
  const float inv = 1.0f / (lpart[idx] + lpart[65536 + idx]);
  float4 rv;
  rv.x = (a.x + c.x) * inv;
  rv.y = (a.y + c.y) * inv;
  rv.z = (a.z + c.z) * inv;
  rv.w = (a.w + c.w) * inv;
  ((float4*)out)[i] = rv;
}

extern "C" void kernel_launch(void* const* d_in, const int* in_sizes, int n_in,
                              void* d_out, int out_size, void* d_ws, size_t ws_size,
                              hipStream_t stream) {
  const float* x  = (const float*)d_in[0];
  const float* Wq = (const float*)d_in[1];
  const float* Wk = (const float*)d_in[2];
  const float* Wv = (const float*)d_in[3];
  float* out = (float*)d_out;

  // layout: [qkv 24MB][xb 8MB][wbt 6MB]; partials alias xb/wbt (dead after proj)
  ushort* qkv = (ushort*)d_ws;                       // q,k: [b][h][s][64]; v: [b*1024+n1][s]
  const size_t per = (size_t)B_ * H_ * S_ * DK_;
  ushort* xb  = qkv + 3 * per;                       // B*S*D bf16
  ushort* wbt = xb + (size_t)B_ * S_ * D_;           // [3072][1024] bf16
  float* opart = (float*)xb;                         // 2 x 16MB fp32 partial O
  float* lpart = opart + (size_t)2 * M_ * D_;        // 2 x 64K fp32 partial lsum

  cvt_all<<<4096 + 768, 256, 0, stream>>>(x, Wq, Wk, Wv, xb, wbt);
  proj_gemm<<<dim3(M_ / 128, N_ / 128), 256, 0, stream>>>(xb, wbt, qkv);
  attn<<<dim3(S_ / 128, B_ * H_, 2), 256, 0, stream>>>(qkv, qkv + per, qkv + 2 * per,
                                                       opart, lpart);
  attn_reduce<<<(M_ * D_) / 4 / 256, 256, 0, stream>>>(opart, lpart, out);
}

// Round 9
// 183.896 us; speedup vs baseline: 1.0007x; 1.0007x over previous
//
#include <hip/hip_runtime.h>

#define B_ 2
#define S_ 2048
#define D_ 1024
#define H_ 16
#define DK_ 64
#define M_ (B_ * S_)   // 4096
#define N_ (3 * D_)    // 3072

typedef __bf16 bf16x8 __attribute__((ext_vector_type(8)));
typedef short s8vec __attribute__((ext_vector_type(8)));
typedef float f4vec __attribute__((ext_vector_type(4)));

static __device__ __forceinline__ ushort f2b(float f) {
  union { float f; unsigned u; } v; v.f = f;
  unsigned u = v.u;
  u += 0x7FFFu + ((u >> 16) & 1u);   // RNE to bf16
  return (ushort)(u >> 16);
}

static __device__ __forceinline__ unsigned pk2(float a, float b) {
#if __has_builtin(__builtin_amdgcn_cvt_pk_bf16_f32)
  typedef __bf16 b2 __attribute__((ext_vector_type(2)));
  b2 r = __builtin_amdgcn_cvt_pk_bf16_f32(a, b);
  return __builtin_bit_cast(unsigned, r);
#else
  return (unsigned)f2b(a) | ((unsigned)f2b(b) << 16);
#endif
}

static __device__ __forceinline__ float fexp2(float x) {
#if __has_builtin(__builtin_amdgcn_exp2f)
  return __builtin_amdgcn_exp2f(x);
#else
  return exp2f(x);
#endif
}

static __device__ __forceinline__ f4vec mfma16(s8vec a, s8vec b, f4vec c) {
  return __builtin_amdgcn_mfma_f32_16x16x32_bf16(
      __builtin_bit_cast(bf16x8, a), __builtin_bit_cast(bf16x8, b), c, 0, 0, 0);
}

static __device__ __forceinline__ void gl_lds16(const ushort* g, ushort* l) {
  __builtin_amdgcn_global_load_lds(
      (const __attribute__((address_space(1))) unsigned*)g,
      (__attribute__((address_space(3))) unsigned*)l, 16, 0, 0);
}

// raw workgroup barrier draining LDS only; in-flight global->VGPR loads cross it
static __device__ __forceinline__ void wg_barrier_lds() {
  asm volatile("" ::: "memory");
  __builtin_amdgcn_s_waitcnt(0xC07F);   // vmcnt(63) expcnt(7) lgkmcnt(0)
  __builtin_amdgcn_s_barrier();
  asm volatile("" ::: "memory");
}

// ---- merged conversion kernel: blocks [0,4096) do x, [4096,4864) do W ----
__global__ __launch_bounds__(256) void cvt_all(const float* __restrict__ x,
                                               const float* __restrict__ Wq,
                                               const float* __restrict__ Wk,
                                               const float* __restrict__ Wv,
                                               ushort* __restrict__ xb,
                                               ushort* __restrict__ wbt) {
  const int t = threadIdx.x;
  if (blockIdx.x < 4096) {
    int i = blockIdx.x * 256 + t;
    float4 v = ((const float4*)x)[i];
    ushort4 o;
    o.x = f2b(v.x); o.y = f2b(v.y); o.z = f2b(v.z); o.w = f2b(v.w);
    ((ushort4*)xb)[i] = o;
  } else {
    __shared__ ushort T[64 * 72];
    int bid = blockIdx.x - 4096;            // 0..767: (w, h, d-tile)
    int w = bid >> 8, rem = bid & 255;
    int h = rem >> 4, d0 = (rem & 15) * 64;
    const float* W = (w == 0) ? Wq : (w == 1) ? Wk : Wv;
    const float* src = W + (size_t)h * 65536 + (size_t)d0 * 64;   // [64 d][64 k]
#pragma unroll
    for (int j = 0; j < 4; ++j) {
      int idx = j * 256 + t;
      int dr = idx >> 4, kc = (idx & 15) * 4;
      float4 v = *(const float4*)(src + dr * 64 + kc);
      T[(kc + 0) * 72 + dr] = f2b(v.x);
      T[(kc + 1) * 72 + dr] = f2b(v.y);
      T[(kc + 2) * 72 + dr] = f2b(v.z);
      T[(kc + 3) * 72 + dr] = f2b(v.w);
    }
    __syncthreads();
    const int kk = t >> 2, dcg = (t & 3) * 16;
    ushort* dst = wbt + ((size_t)w * 1024 + h * 64 + kk) * 1024 + d0 + dcg;
    *(s8vec*)dst       = *(const s8vec*)&T[kk * 72 + dcg];
    *(s8vec*)(dst + 8) = *(const s8vec*)&T[kk * 72 + dcg + 8];
  }
}

// ---- fused QKV projection: C[4096][3072] = X[4096][1024] @ Wbt^T (m97 core) ----
// NEW: epilogue goes through per-wave LDS scratch (reusing As/Bs) and emits
// coalesced b128 global stores (was: 64 scalar 2B stores per thread).
__global__ __launch_bounds__(256) void proj_gemm(const ushort* __restrict__ xb,
                                                 const ushort* __restrict__ wbt,
                                                 ushort* __restrict__ qkv) {
  __shared__ __attribute__((aligned(16))) ushort BUF[2 * 128 * 64];  // As | Bs, 32KB
  ushort* As = BUF;
  ushort* Bs = BUF + 128 * 64;
  const int tid = threadIdx.x, wid = tid >> 6, lane = tid & 63;
  const int quad = lane >> 4, l15 = lane & 15;
  const int wm = wid & 1, wn = wid >> 1;
  const int m0 = blockIdx.x * 128, n0 = blockIdx.y * 128;

  f4vec acc[4][4];
#pragma unroll
  for (int mb = 0; mb < 4; mb++)
#pragma unroll
    for (int nb = 0; nb < 4; nb++)
#pragma unroll
      for (int i = 0; i < 4; i++) acc[mb][nb][i] = 0.f;

  const int sr = tid >> 3, sg = tid & 7;
  const int lg = sg ^ (sr & 7);
  const ushort* Ab = xb + (size_t)m0 * D_;
  const ushort* Bb = wbt + (size_t)n0 * D_;

  for (int k0 = 0; k0 < D_; k0 += 64) {
    __syncthreads();
#pragma unroll
    for (int j = 0; j < 4; ++j) {
      int r = j * 32 + sr;
      gl_lds16(Ab + (size_t)r * D_ + k0 + lg * 8, &As[j * 2048 + wid * 512]);
      gl_lds16(Bb + (size_t)r * D_ + k0 + lg * 8, &Bs[j * 2048 + wid * 512]);
    }
    __syncthreads();

#pragma unroll
    for (int kb = 0; kb < 2; ++kb) {
      s8vec af[4], bf[4];
#pragma unroll
      for (int mb = 0; mb < 4; ++mb) {
        int m = wm * 64 + mb * 16 + l15;
        int gpos = (kb * 4 + quad) ^ (m & 7);
        af[mb] = *(const s8vec*)&As[m * 64 + gpos * 8];
      }
#pragma unroll
      for (int nb = 0; nb < 4; ++nb) {
        int n = wn * 64 + nb * 16 + l15;
        int gpos = (kb * 4 + quad) ^ (n & 7);
        bf[nb] = *(const s8vec*)&Bs[n * 64 + gpos * 8];
      }
#pragma unroll
      for (int mb = 0; mb < 4; ++mb)
#pragma unroll
        for (int nb = 0; nb < 4; ++nb)
          acc[mb][nb] = mfma16(af[mb], bf[nb], acc[mb][nb]);
    }
  }

  __syncthreads();                       // done reading As/Bs; reuse as scratch
  ushort* T = BUF + wid * 4096;          // per-wave 64x64 scratch (8KB)
  const size_t per = (size_t)B_ * H_ * S_ * DK_;
  const int w = n0 >> 10;
  const int sb = m0 + wm * 64;           // wave's global m base
  const int b = sb >> 11;                // batch (const per wave)
  const int nb0 = (n0 & 1023) + wn * 64; // wave's n base (multiple of 64)

  if (w == 2) {
    // scratch layout T[n'][swizzled m'] ; b64 writes (4 consecutive m' per reg)
#pragma unroll
    for (int mb = 0; mb < 4; ++mb) {
      const int mc = mb * 2 + (quad >> 1);           // m'-chunk
      const int moff = (quad & 1) * 4;
#pragma unroll
      for (int nb = 0; nb < 4; ++nb) {
        const int np = nb * 16 + l15;
        unsigned p01 = pk2(acc[mb][nb][0], acc[mb][nb][1]);
        unsigned p23 = pk2(acc[mb][nb][2], acc[mb][nb][3]);
        *(uint2*)&T[np * 64 + ((mc ^ (np & 7)) * 8) + moff] = make_uint2(p01, p23);
      }
    }
    // read rows of m' (vector) and store coalesced along s
    ushort* vt = qkv + 2 * per;
#pragma unroll
    for (int j = 0; j < 8; ++j) {
      const int np = (lane >> 3) + j * 8;
      const int mc2 = lane & 7;
      s8vec v = *(const s8vec*)&T[np * 64 + ((mc2 ^ (np & 7)) * 8)];
      const int n1 = nb0 + np;
      *(s8vec*)(vt + ((size_t)b * 1024 + n1) * S_ + (sb & 2047) + mc2 * 8) = v;
    }
  } else {
    const float qs = (w == 0) ? 1.44269504f : 1.0f;  // log2(e) pre-scale for exp2
    // scratch layout T[m'][swizzled n'] ; scalar writes (cheap LDS, once)
#pragma unroll
    for (int mb = 0; mb < 4; ++mb)
#pragma unroll
      for (int nb = 0; nb < 4; ++nb) {
        const int c = nb * 2 + (l15 >> 3);
#pragma unroll
        for (int i = 0; i < 4; ++i) {
          const int mp = mb * 16 + quad * 4 + i;
          T[mp * 64 + ((c ^ (mp & 7)) * 8) + (l15 & 7)] = f2b(acc[mb][nb][i] * qs);
        }
      }
    // read rows of n' (vector) and store coalesced along n
    const int h = nb0 >> 6;
    ushort* qk = qkv + (size_t)w * per + (((size_t)b * H_ + h) * S_) * 64;
#pragma unroll
    for (int j = 0; j < 8; ++j) {
      const int mp = (lane >> 3) + j * 8;
      const int c2 = lane & 7;
      s8vec v = *(const s8vec*)&T[mp * 64 + ((c2 ^ (mp & 7)) * 8)];
      *(s8vec*)(qk + (size_t)((sb & 2047) + mp) * 64 + c2 * 8) = v;
    }
  }
}

// ---- flash attention v7: z=1, 128 threads (2 waves x 32 q = Q-tile 64),
// K-tile 64, grid (32,32) = 1024 blocks -> 4 blocks/CU. S^T layout, ones-row
// lsum, b64 P-writes, exp2, reg-prefetch double buffering. Direct fp32 output.
__global__ __launch_bounds__(128) void attn(const ushort* __restrict__ qg,
                                            const ushort* __restrict__ kg,
                                            const ushort* __restrict__ vtg,
                                            float* __restrict__ out) {
  __shared__ __attribute__((aligned(16))) ushort Ks[64 * 64];      // [key][d]
  __shared__ __attribute__((aligned(16))) ushort Vt[80 * 64];      // [dv(+ones)][key]
  __shared__ __attribute__((aligned(16))) ushort Ps[2][32 * 64];   // [q][key]
  const int qt = blockIdx.x, bh = blockIdx.y;
  const int b = bh >> 4, h = bh & 15;
  const int tid = threadIdx.x, wid = tid >> 6, lane = tid & 63;
  const int quad = lane >> 4, l15 = lane & 15, l7 = l15 & 7;

  // ones rows 64..79 of Vt (bf16 1.0 = 0x3F80), written once
  {
    ushort* p = &Vt[(64 + (tid >> 3)) * 64 + (tid & 7) * 8];
#pragma unroll
    for (int j = 0; j < 8; ++j) p[j] = 0x3F80;
  }

  // Q fragments (B-operand: n=q, k=d); wave owns q rows qt*64 + wid*32 + mb*16 + l15
  const ushort* qbase = qg + ((size_t)bh * S_ + qt * 64 + wid * 32) * DK_;
  s8vec aq[2][2];
#pragma unroll
  for (int mb = 0; mb < 2; mb++) {
    aq[mb][0] = *(const s8vec*)(qbase + (size_t)(mb * 16 + l15) * DK_ + quad * 8);
    aq[mb][1] = *(const s8vec*)(qbase + (size_t)(mb * 16 + l15) * DK_ + 32 + quad * 8);
  }

  f4vec o[2][5];          // O^T[dv-block nb][q]; nb=4 is the ones-row (lsum)
#pragma unroll
  for (int mb = 0; mb < 2; mb++)
#pragma unroll
    for (int nb = 0; nb < 5; nb++)
#pragma unroll
      for (int i = 0; i < 4; i++) o[mb][nb][i] = 0.f;

  // staging (128 threads): thread t -> rows {r0, r0+16, r0+32, r0+48}; slot gs
  const int r0 = tid >> 3, gs = tid & 7;
  const int gk = gs ^ (r0 & 7);           // (r0+16k)&7 == r0&7
  const ushort* kb_ = kg + (size_t)bh * S_ * DK_;
  const ushort* vb_ = vtg + (size_t)bh * 64 * S_;

  s8vec kpre[4], vpre[4];
#pragma unroll
  for (int j = 0; j < 4; ++j) {
    kpre[j] = *(const s8vec*)(kb_ + (size_t)(j * 16 + r0) * DK_ + gk * 8);
    vpre[j] = *(const s8vec*)(vb_ + (size_t)(j * 16 + r0) * S_ + gk * 8);
  }

  for (int kt = 0; kt < S_ / 64; ++kt) {
    wg_barrier_lds();                      // readers of previous tile done
#pragma unroll
    for (int j = 0; j < 4; ++j) {
      *(s8vec*)&Ks[(j * 16 + r0) * 64 + gs * 8] = kpre[j];   // vmcnt auto-waits
      *(s8vec*)&Vt[(j * 16 + r0) * 64 + gs * 8] = vpre[j];
    }
    if (kt + 1 < S_ / 64) {               // prefetch next tile; stays in flight
      const ushort* kn = kb_ + (size_t)((kt + 1) * 64 + r0) * DK_ + gk * 8;
      const ushort* vn = vb_ + (size_t)r0 * S_ + (kt + 1) * 64 + gk * 8;
#pragma unroll
      for (int j = 0; j < 4; ++j) {
        kpre[j] = *(const s8vec*)(kn + (size_t)(j * 16) * DK_);
        vpre[j] = *(const s8vec*)(vn + (size_t)(j * 16) * S_);
      }
    }
    wg_barrier_lds();                      // staging writes visible

    // S^T = K Q^T : A-frag = Ks rows (m=key), B = Q regs (n=q)
    f4vec sct[2][4];
#pragma unroll
    for (int nb = 0; nb < 4; nb++) {
      const int row = nb * 16 + l15;
      s8vec ak0 = *(const s8vec*)&Ks[row * 64 + ((0 + quad) ^ l7) * 8];
      s8vec ak1 = *(const s8vec*)&Ks[row * 64 + ((4 + quad) ^ l7) * 8];
#pragma unroll
      for (int mb = 0; mb < 2; mb++) {
        f4vec z;
#pragma unroll
        for (int i = 0; i < 4; i++) z[i] = 0.f;
        z = mfma16(ak0, aq[mb][0], z);
        sct[mb][nb] = mfma16(ak1, aq[mb][1], z);
      }
    }

    // softmax: exp2 (Q pre-scaled), 4 consecutive keys -> one b64 LDS write
#pragma unroll
    for (int mb = 0; mb < 2; mb++) {
      const int q = mb * 16 + l15;
#pragma unroll
      for (int nb = 0; nb < 4; nb++) {
        f4vec p;
#pragma unroll
        for (int i = 0; i < 4; i++) p[i] = fexp2(sct[mb][nb][i]);
        unsigned p01 = pk2(p[0], p[1]);
        unsigned p23 = pk2(p[2], p[3]);
        const int c = (nb * 2 + (quad >> 1)) ^ l7;
        *(uint2*)&Ps[wid][q * 64 + c * 8 + (quad & 1) * 4] = make_uint2(p01, p23);
      }
    }
    // no barrier: Ps[wid] per-wave

    // O^T += V^T P^T : A = Vt rows (m=dv, nb=4 -> ones/lsum), B = Ps rows (n=q)
#pragma unroll
    for (int kc = 0; kc < 2; kc++) {
      s8vec ap[2];
#pragma unroll
      for (int mb = 0; mb < 2; mb++)
        ap[mb] = *(const s8vec*)&Ps[wid][(mb * 16 + l15) * 64 + ((kc * 4 + quad) ^ l7) * 8];
#pragma unroll
      for (int nb = 0; nb < 5; nb++) {
        s8vec av = *(const s8vec*)&Vt[(nb * 16 + l15) * 64 + ((kc * 4 + quad) ^ l7) * 8];
        o[0][nb] = mfma16(av, ap[0], o[0][nb]);
        o[1][nb] = mfma16(av, ap[1], o[1][nb]);
      }
    }
  }

  // epilogue: normalize by lsum (= ones-row accumulator, same for all quads/i)
#pragma unroll
  for (int mb = 0; mb < 2; mb++) {
    const float inv = 1.0f / o[mb][4][0];
    float* ob = out + ((size_t)b * S_ + qt * 64 + wid * 32 + mb * 16 + l15) * D_ + h * DK_;
#pragma unroll
    for (int nb = 0; nb < 4; nb++) {
      float4 v;
      v.x = o[mb][nb][0] * inv;
      v.y = o[mb][nb][1] * inv;
      v.z = o[mb][nb][2] * inv;
      v.w = o[mb][nb][3] * inv;
      *(float4*)(ob + nb * 16 + quad * 4) = v;
    }
  }
}

extern "C" void kernel_launch(void* const* d_in, const int* in_sizes, int n_in,
                              void* d_out, int out_size, void* d_ws, size_t ws_size,
                              hipStream_t stream) {
  const float* x  = (const float*)d_in[0];
  const float* Wq = (const float*)d_in[1];
  const float* Wk = (const float*)d_in[2];
  const float* Wv = (const float*)d_in[3];
  float* out = (float*)d_out;

  ushort* qkv = (ushort*)d_ws;                       // q,k: [b][h][s][64]; v: [b*1024+n1][s]
  const size_t per = (size_t)B_ * H_ * S_ * DK_;
  ushort* xb  = qkv + 3 * per;                       // B*S*D bf16
  ushort* wbt = xb + (size_t)B_ * S_ * D_;           // [3072][1024] bf16

  cvt_all<<<4096 + 768, 256, 0, stream>>>(x, Wq, Wk, Wv, xb, wbt);
  proj_gemm<<<dim3(M_ / 128, N_ / 128), 256, 0, stream>>>(xb, wbt, qkv);
  attn<<<dim3(S_ / 64, B_ * H_), 128, 0, stream>>>(qkv, qkv + per, qkv + 2 * per, out);
}

// Round 10
// 175.962 us; speedup vs baseline: 1.0459x; 1.0451x over previous
//
#include <hip/hip_runtime.h>

#define B_ 2
#define S_ 2048
#define D_ 1024
#define H_ 16
#define DK_ 64
#define M_ (B_ * S_)   // 4096
#define N_ (3 * D_)    // 3072

typedef __bf16 bf16x8 __attribute__((ext_vector_type(8)));
typedef short s8vec __attribute__((ext_vector_type(8)));
typedef float f4vec __attribute__((ext_vector_type(4)));

static __device__ __forceinline__ ushort f2b(float f) {
  union { float f; unsigned u; } v; v.f = f;
  unsigned u = v.u;
  u += 0x7FFFu + ((u >> 16) & 1u);   // RNE to bf16
  return (ushort)(u >> 16);
}

static __device__ __forceinline__ unsigned pk2(float a, float b) {
#if __has_builtin(__builtin_amdgcn_cvt_pk_bf16_f32)
  typedef __bf16 b2 __attribute__((ext_vector_type(2)));
  b2 r = __builtin_amdgcn_cvt_pk_bf16_f32(a, b);
  return __builtin_bit_cast(unsigned, r);
#else
  return (unsigned)f2b(a) | ((unsigned)f2b(b) << 16);
#endif
}

static __device__ __forceinline__ float fexp2(float x) {
#if __has_builtin(__builtin_amdgcn_exp2f)
  return __builtin_amdgcn_exp2f(x);
#else
  return exp2f(x);
#endif
}

static __device__ __forceinline__ f4vec mfma16(s8vec a, s8vec b, f4vec c) {
  return __builtin_amdgcn_mfma_f32_16x16x32_bf16(
      __builtin_bit_cast(bf16x8, a), __builtin_bit_cast(bf16x8, b), c, 0, 0, 0);
}

static __device__ __forceinline__ void gl_lds16(const ushort* g, ushort* l) {
  __builtin_amdgcn_global_load_lds(
      (const __attribute__((address_space(1))) unsigned*)g,
      (__attribute__((address_space(3))) unsigned*)l, 16, 0, 0);
}

// raw workgroup barrier draining LDS only; in-flight global->VGPR loads cross it
static __device__ __forceinline__ void wg_barrier_lds() {
  asm volatile("" ::: "memory");
  __builtin_amdgcn_s_waitcnt(0xC07F);   // vmcnt(63) expcnt(7) lgkmcnt(0)
  __builtin_amdgcn_s_barrier();
  asm volatile("" ::: "memory");
}

// ---- merged conversion kernel: blocks [0,4096) do x, [4096,4864) do W ----
__global__ __launch_bounds__(256) void cvt_all(const float* __restrict__ x,
                                               const float* __restrict__ Wq,
                                               const float* __restrict__ Wk,
                                               const float* __restrict__ Wv,
                                               ushort* __restrict__ xb,
                                               ushort* __restrict__ wbt) {
  const int t = threadIdx.x;
  if (blockIdx.x < 4096) {
    int i = blockIdx.x * 256 + t;
    float4 v = ((const float4*)x)[i];
    ushort4 o;
    o.x = f2b(v.x); o.y = f2b(v.y); o.z = f2b(v.z); o.w = f2b(v.w);
    ((ushort4*)xb)[i] = o;
  } else {
    __shared__ ushort T[64 * 72];
    int bid = blockIdx.x - 4096;            // 0..767: (w, h, d-tile)
    int w = bid >> 8, rem = bid & 255;
    int h = rem >> 4, d0 = (rem & 15) * 64;
    const float* W = (w == 0) ? Wq : (w == 1) ? Wk : Wv;
    const float* src = W + (size_t)h * 65536 + (size_t)d0 * 64;   // [64 d][64 k]
#pragma unroll
    for (int j = 0; j < 4; ++j) {
      int idx = j * 256 + t;
      int dr = idx >> 4, kc = (idx & 15) * 4;
      float4 v = *(const float4*)(src + dr * 64 + kc);
      T[(kc + 0) * 72 + dr] = f2b(v.x);
      T[(kc + 1) * 72 + dr] = f2b(v.y);
      T[(kc + 2) * 72 + dr] = f2b(v.z);
      T[(kc + 3) * 72 + dr] = f2b(v.w);
    }
    __syncthreads();
    const int kk = t >> 2, dcg = (t & 3) * 16;
    ushort* dst = wbt + ((size_t)w * 1024 + h * 64 + kk) * 1024 + d0 + dcg;
    *(s8vec*)dst       = *(const s8vec*)&T[kk * 72 + dcg];
    *(s8vec*)(dst + 8) = *(const s8vec*)&T[kk * 72 + dcg + 8];
  }
}

// ---- fused QKV projection: C[4096][3072] = X[4096][1024] @ Wbt^T (m97 core,
// vectorized LDS-transpose epilogue). Q pre-scaled by log2(e). ----
__global__ __launch_bounds__(256) void proj_gemm(const ushort* __restrict__ xb,
                                                 const ushort* __restrict__ wbt,
                                                 ushort* __restrict__ qkv) {
  __shared__ __attribute__((aligned(16))) ushort BUF[2 * 128 * 64];  // As | Bs, 32KB
  ushort* As = BUF;
  ushort* Bs = BUF + 128 * 64;
  const int tid = threadIdx.x, wid = tid >> 6, lane = tid & 63;
  const int quad = lane >> 4, l15 = lane & 15;
  const int wm = wid & 1, wn = wid >> 1;
  const int m0 = blockIdx.x * 128, n0 = blockIdx.y * 128;

  f4vec acc[4][4];
#pragma unroll
  for (int mb = 0; mb < 4; mb++)
#pragma unroll
    for (int nb = 0; nb < 4; nb++)
#pragma unroll
      for (int i = 0; i < 4; i++) acc[mb][nb][i] = 0.f;

  const int sr = tid >> 3, sg = tid & 7;
  const int lg = sg ^ (sr & 7);
  const ushort* Ab = xb + (size_t)m0 * D_;
  const ushort* Bb = wbt + (size_t)n0 * D_;

  for (int k0 = 0; k0 < D_; k0 += 64) {
    __syncthreads();
#pragma unroll
    for (int j = 0; j < 4; ++j) {
      int r = j * 32 + sr;
      gl_lds16(Ab + (size_t)r * D_ + k0 + lg * 8, &As[j * 2048 + wid * 512]);
      gl_lds16(Bb + (size_t)r * D_ + k0 + lg * 8, &Bs[j * 2048 + wid * 512]);
    }
    __syncthreads();

#pragma unroll
    for (int kb = 0; kb < 2; ++kb) {
      s8vec af[4], bf[4];
#pragma unroll
      for (int mb = 0; mb < 4; ++mb) {
        int m = wm * 64 + mb * 16 + l15;
        int gpos = (kb * 4 + quad) ^ (m & 7);
        af[mb] = *(const s8vec*)&As[m * 64 + gpos * 8];
      }
#pragma unroll
      for (int nb = 0; nb < 4; ++nb) {
        int n = wn * 64 + nb * 16 + l15;
        int gpos = (kb * 4 + quad) ^ (n & 7);
        bf[nb] = *(const s8vec*)&Bs[n * 64 + gpos * 8];
      }
#pragma unroll
      for (int mb = 0; mb < 4; ++mb)
#pragma unroll
        for (int nb = 0; nb < 4; ++nb)
          acc[mb][nb] = mfma16(af[mb], bf[nb], acc[mb][nb]);
    }
  }

  __syncthreads();                       // done reading As/Bs; reuse as scratch
  ushort* T = BUF + wid * 4096;          // per-wave 64x64 scratch (8KB)
  const size_t per = (size_t)B_ * H_ * S_ * DK_;
  const int w = n0 >> 10;
  const int sb = m0 + wm * 64;           // wave's global m base
  const int b = sb >> 11;                // batch (const per wave)
  const int nb0 = (n0 & 1023) + wn * 64; // wave's n base (multiple of 64)

  if (w == 2) {
#pragma unroll
    for (int mb = 0; mb < 4; ++mb) {
      const int mc = mb * 2 + (quad >> 1);
      const int moff = (quad & 1) * 4;
#pragma unroll
      for (int nb = 0; nb < 4; ++nb) {
        const int np = nb * 16 + l15;
        unsigned p01 = pk2(acc[mb][nb][0], acc[mb][nb][1]);
        unsigned p23 = pk2(acc[mb][nb][2], acc[mb][nb][3]);
        *(uint2*)&T[np * 64 + ((mc ^ (np & 7)) * 8) + moff] = make_uint2(p01, p23);
      }
    }
    ushort* vt = qkv + 2 * per;
#pragma unroll
    for (int j = 0; j < 8; ++j) {
      const int np = (lane >> 3) + j * 8;
      const int mc2 = lane & 7;
      s8vec v = *(const s8vec*)&T[np * 64 + ((mc2 ^ (np & 7)) * 8)];
      const int n1 = nb0 + np;
      *(s8vec*)(vt + ((size_t)b * 1024 + n1) * S_ + (sb & 2047) + mc2 * 8) = v;
    }
  } else {
    const float qs = (w == 0) ? 1.44269504f : 1.0f;  // log2(e) pre-scale for exp2
#pragma unroll
    for (int mb = 0; mb < 4; ++mb)
#pragma unroll
      for (int nb = 0; nb < 4; ++nb) {
        const int c = nb * 2 + (l15 >> 3);
#pragma unroll
        for (int i = 0; i < 4; ++i) {
          const int mp = mb * 16 + quad * 4 + i;
          T[mp * 64 + ((c ^ (mp & 7)) * 8) + (l15 & 7)] = f2b(acc[mb][nb][i] * qs);
        }
      }
    const int h = nb0 >> 6;
    ushort* qk = qkv + (size_t)w * per + (((size_t)b * H_ + h) * S_) * 64;
#pragma unroll
    for (int j = 0; j < 8; ++j) {
      const int mp = (lane >> 3) + j * 8;
      const int c2 = lane & 7;
      s8vec v = *(const s8vec*)&T[mp * 64 + ((c2 ^ (mp & 7)) * 8)];
      *(s8vec*)(qk + (size_t)((sb & 2047) + mp) * 64 + c2 * 8) = v;
    }
  }
}

// ---- flash attention v8: r5 shape (512 thr, 8 waves x 16 q = Q-tile 128,
// K-tile 128, reg-prefetch dbuf, 2 blocks/CU = 16 waves/CU) + S^T layout,
// ones-row lsum, exp2, b64 P-writes, float4 epilogue. LDS 68KB.
__global__ __launch_bounds__(512) void attn(const ushort* __restrict__ qg,
                                            const ushort* __restrict__ kg,
                                            const ushort* __restrict__ vtg,
                                            float* __restrict__ out) {
  __shared__ __attribute__((aligned(16))) ushort Ks[128 * 64];      // [key][d]
  __shared__ __attribute__((aligned(16))) ushort Vt[80 * 128];      // [dv(+ones)][key]
  __shared__ __attribute__((aligned(16))) ushort Ps[8][16 * 128];   // [q][key]
  const int qt = blockIdx.x, bh = blockIdx.y;
  const int b = bh >> 4, h = bh & 15;
  const int tid = threadIdx.x, wid = tid >> 6, lane = tid & 63;
  const int quad = lane >> 4, l15 = lane & 15, l7 = l15 & 7;

  // ones rows 64..79 of Vt (bf16 1.0), written once (no swizzle needed: constant)
  if (tid < 256) {
    ushort* p = &Vt[(64 + (tid >> 4)) * 128 + (tid & 15) * 8];
#pragma unroll
    for (int j = 0; j < 8; ++j) p[j] = 0x3F80;
  }

  // Q fragments (B-operand: n=q=l15, k=d); wave owns q rows qt*128 + wid*16 + l15
  const ushort* qbase = qg + ((size_t)bh * S_ + qt * 128 + wid * 16) * DK_;
  s8vec aq0 = *(const s8vec*)(qbase + (size_t)l15 * DK_ + quad * 8);
  s8vec aq1 = *(const s8vec*)(qbase + (size_t)l15 * DK_ + 32 + quad * 8);

  f4vec o[5];             // O^T[dv-block nb][q=l15]; nb=4 is the ones-row (lsum)
#pragma unroll
  for (int nb = 0; nb < 5; nb++)
#pragma unroll
    for (int i = 0; i < 4; i++) o[nb][i] = 0.f;

  // staging: K: thread t -> rows {r, r+64}, slot gs, global chunk gk=gs^(r&7)
  //          V^T: thread t -> rows {rv, rv+32}, slot cs (0..15), chunk gv
  const int r = tid >> 3, gs = tid & 7;
  const int gk = gs ^ (r & 7);
  const int rv = tid >> 4, cs = tid & 15;
  const int gv = (cs & 8) | ((cs & 7) ^ (rv & 7));
  const ushort* kb_ = kg + (size_t)bh * S_ * DK_;
  const ushort* vb_ = vtg + (size_t)bh * 64 * S_;

  s8vec kpre[2], vpre[2];
  kpre[0] = *(const s8vec*)(kb_ + (size_t)r * DK_ + gk * 8);
  kpre[1] = *(const s8vec*)(kb_ + (size_t)(r + 64) * DK_ + gk * 8);
  vpre[0] = *(const s8vec*)(vb_ + (size_t)rv * S_ + gv * 8);
  vpre[1] = *(const s8vec*)(vb_ + (size_t)(rv + 32) * S_ + gv * 8);

  for (int kt = 0; kt < S_ / 128; ++kt) {
    wg_barrier_lds();                      // readers of previous tile done
    *(s8vec*)&Ks[r * 64 + gs * 8]          = kpre[0];   // vmcnt auto-waits
    *(s8vec*)&Ks[(r + 64) * 64 + gs * 8]   = kpre[1];
    *(s8vec*)&Vt[rv * 128 + cs * 8]        = vpre[0];
    *(s8vec*)&Vt[(rv + 32) * 128 + cs * 8] = vpre[1];
    if (kt + 1 < S_ / 128) {              // prefetch next tile; stays in flight
      const ushort* kn = kb_ + (size_t)((kt + 1) * 128 + r) * DK_ + gk * 8;
      kpre[0] = *(const s8vec*)(kn);
      kpre[1] = *(const s8vec*)(kn + (size_t)64 * DK_);
      const ushort* vn = vb_ + (size_t)rv * S_ + (kt + 1) * 128 + gv * 8;
      vpre[0] = *(const s8vec*)(vn);
      vpre[1] = *(const s8vec*)(vn + (size_t)32 * S_);
    }
    wg_barrier_lds();                      // staging writes visible

    // S^T = K Q^T per 16-key block; exp2; b64 P-write into per-wave Ps
#pragma unroll
    for (int nb = 0; nb < 8; nb++) {
      const int row = nb * 16 + l15;
      s8vec ak0 = *(const s8vec*)&Ks[row * 64 + ((0 + quad) ^ l7) * 8];
      s8vec ak1 = *(const s8vec*)&Ks[row * 64 + ((4 + quad) ^ l7) * 8];
      f4vec z;
#pragma unroll
      for (int i = 0; i < 4; i++) z[i] = 0.f;
      z = mfma16(ak0, aq0, z);
      z = mfma16(ak1, aq1, z);
      f4vec p;
#pragma unroll
      for (int i = 0; i < 4; i++) p[i] = fexp2(z[i]);
      unsigned p01 = pk2(p[0], p[1]);
      unsigned p23 = pk2(p[2], p[3]);
      const int c = (nb * 2 + (quad >> 1)) ^ l7;   // key-chunk, swizzled by q&7
      *(uint2*)&Ps[wid][l15 * 128 + c * 8 + (quad & 1) * 4] = make_uint2(p01, p23);
    }
    // no barrier: Ps[wid] per-wave (intra-wave lgkm ordering suffices)

    // O^T += V^T P^T : A = Vt rows (m=dv; nb=4 -> ones/lsum), B = Ps rows (n=q)
#pragma unroll
    for (int kc = 0; kc < 4; kc++) {
      s8vec ap = *(const s8vec*)&Ps[wid][l15 * 128 + ((kc * 4 + quad) ^ l7) * 8];
#pragma unroll
      for (int nb = 0; nb < 5; nb++) {
        s8vec av = *(const s8vec*)&Vt[(nb * 16 + l15) * 128 + ((kc * 4 + quad) ^ l7) * 8];
        o[nb] = mfma16(av, ap, o[nb]);
      }
    }
  }

  // epilogue: normalize by lsum (= ones-row accumulator) and store float4
  const float inv = 1.0f / o[4][0];
  float* ob = out + ((size_t)b * S_ + qt * 128 + wid * 16 + l15) * D_ + h * DK_;
#pragma unroll
  for (int nb = 0; nb < 4; nb++) {
    float4 v;
    v.x = o[nb][0] * inv;
    v.y = o[nb][1] * inv;
    v.z = o[nb][2] * inv;
    v.w = o[nb][3] * inv;
    *(float4*)(ob + nb * 16 + quad * 4) = v;
  }
}

extern "C" void kernel_launch(void* const* d_in, const int* in_sizes, int n_in,
                              void* d_out, int out_size, void* d_ws, size_t ws_size,
                              hipStream_t stream) {
  const float* x  = (const float*)d_in[0];
  const float* Wq = (const float*)d_in[1];
  const float* Wk = (const float*)d_in[2];
  const float* Wv = (const float*)d_in[3];
  float* out = (float*)d_out;

  ushort* qkv = (ushort*)d_ws;                       // q,k: [b][h][s][64]; v: [b*1024+n1][s]
  const size_t per = (size_t)B_ * H_ * S_ * DK_;
  ushort* xb  = qkv + 3 * per;                       // B*S*D bf16
  ushort* wbt = xb + (size_t)B_ * S_ * D_;           // [3072][1024] bf16

  cvt_all<<<4096 + 768, 256, 0, stream>>>(x, Wq, Wk, Wv, xb, wbt);
  proj_gemm<<<dim3(M_ / 128, N_ / 128), 256, 0, stream>>>(xb, wbt, qkv);
  attn<<<dim3(S_ / 128, B_ * H_), 512, 0, stream>>>(qkv, qkv + per, qkv + 2 * per, out);
}